// Round 7
// baseline (198.047 us; speedup 1.0000x reference)
//
#include <hip/hip_runtime.h>
#include <math.h>

#define BB 16
#define PP (768*768)        // 589824
#define NBINS 4096
#define CHUNKS 96           // blocks per image; pixels/block = 6144
#define PIXB (PP / CHUNKS)  // 6144
#define KALL 176947         // int(P * 0.3)

#define LOV_LO (-17.0f)
#define LOV_RANGE 34.0f

typedef unsigned long long u64;

struct PAcc { float pos_sum, pos_w, tpx, sprx, mx, sum_t, n_tis, bce0; };   // 32 B
struct AccR { float lov_i, ft_i, ohem_i; unsigned posb; };                  // 16 B

__device__ inline float wred_sum(float v) {
  #pragma unroll
  for (int o = 32; o > 0; o >>= 1) v += __shfl_down(v, o, 64);
  return v;
}
__device__ inline float wred_max(float v) {
  #pragma unroll
  for (int o = 32; o > 0; o >>= 1) v = fmaxf(v, __shfl_down(v, o, 64));
  return v;
}

// ---------------- K1: fused pass; one LDS atomic/px; x2-unrolled loads ----------------
__global__ __launch_bounds__(256, 6) void k_main(const float* __restrict__ logits,
                                                 const int* __restrict__ targets,
                                                 const float* __restrict__ mask,
                                                 PAcc* __restrict__ pacc,
                                                 unsigned* __restrict__ partial1,
                                                 unsigned* __restrict__ partial3,
                                                 unsigned* __restrict__ flags,
                                                 unsigned* __restrict__ tickets)
{
  const int b = blockIdx.y;
  const int chunk = blockIdx.x;
  __shared__ unsigned hist1[NBINS];        // count | pos<<16   (16 KB)
  __shared__ unsigned hist3p[NBINS / 2];   // packed u16: #(t==0 && m!=1)  (8 KB)
  __shared__ float wsum[4][8];
  __shared__ unsigned s_any3;
  for (int i = threadIdx.x; i < NBINS; i += 256) hist1[i] = 0u;
  for (int i = threadIdx.x; i < NBINS / 2; i += 256) hist3p[i] = 0u;
  // zero tickets for k_tail (runs strictly after all k_main blocks)
  if (b == 0 && chunk == 0 && threadIdx.x < 17) tickets[threadIdx.x] = 0u;
  __syncthreads();

  const float4* l4 = (const float4*)(logits + (size_t)b * PP);
  const int4*   t4 = (const int4*)(targets + (size_t)b * PP);
  const float4* m4 = (const float4*)(mask + (size_t)b * PP);

  const float lov_scale = (float)NBINS / LOV_RANGE;

  float pos_sum = 0.f, pos_w = 0.f, tpa = 0.f, spra = 0.f, mx = 0.f;
  float sum_t = 0.f, n_tis = 0.f, bce0 = 0.f;

  // fallback loss_i[0] (chunk 0 / thread 0 only; block-sum propagates it)
  if (chunk == 0 && threadIdx.x == 0) {
    float l = logits[(size_t)b * PP];
    float tf = (float)targets[(size_t)b * PP];
    float m = mask[(size_t)b * PP];
    float ex = __expf(-fabsf(l));
    bce0 = (fmaxf(l, 0.f) + __logf(1.f + ex) - l * tf) * m;
  }

  auto px = [&](float l, int ti, float m) {
    float tf = (float)ti;
    float ex = __expf(-fabsf(l));                    // e^{-|l|}
    float lg = __logf(1.f + ex);                     // log1p(exp(-|l|)), 1+ex in (1,2]
    float loss = (fmaxf(l, 0.f) + lg - l * tf) * m;  // bce * mask
    float posw = tf * m;
    pos_sum = fmaf(loss, posw, pos_sum);
    pos_w  += posw;
    float pr = ((l >= 0.f) ? 1.f : ex) * __builtin_amdgcn_rcpf(1.f + ex);  // sigmoid
    spra += pr;
    tpa = fmaf(pr, tf, tpa);
    sum_t += tf;
    bool tis = (m == 1.0f);
    if (tis) { n_tis += 1.f; mx = fmaxf(mx, loss); }
    float s = fmaf(2.f, tf, -1.f);
    float e = fmaf(-l, s, 1.f);                      // lovasz error
    int bin = (int)((e - LOV_LO) * lov_scale);
    bin = bin < 0 ? 0 : (bin > NBINS - 1 ? NBINS - 1 : bin);
    atomicAdd(&hist1[bin], 1u | ((unsigned)ti << 16));
    if ((ti == 0) & !tis)                            // never fires when mask==1
      atomicAdd(&hist3p[bin >> 1], 1u << ((bin & 1) << 4));
  };
  auto grp = [&](float4 lv, int4 tv, float4 mv) {
    px(lv.x, tv.x, mv.x); px(lv.y, tv.y, mv.y);
    px(lv.z, tv.z, mv.z); px(lv.w, tv.w, mv.w);
  };

  const int per_chunk4 = PIXB / 4;                   // 1536
  const int base4 = chunk * per_chunk4;
  const int iters = per_chunk4 / 256;                // 6

  for (int it = 0; it < iters; it += 2) {
    int ia = base4 + it * 256 + threadIdx.x;
    int ib = ia + 256;
    float4 lva = l4[ia]; float4 lvb = l4[ib];
    int4   tva = t4[ia]; int4   tvb = t4[ib];
    float4 mva = m4[ia]; float4 mvb = m4[ib];
    grp(lva, tva, mva);
    grp(lvb, tvb, mvb);
  }

  // block-level scalar reduction -> pacc (non-atomic)
  {
    float v0 = wred_sum(pos_sum), v1 = wred_sum(pos_w), v2 = wred_sum(tpa);
    float v3 = wred_sum(spra), v4 = wred_max(mx), v5 = wred_sum(sum_t);
    float v6 = wred_sum(n_tis), v7 = wred_sum(bce0);
    int w = threadIdx.x >> 6, lane = threadIdx.x & 63;
    if (lane == 0) {
      wsum[w][0] = v0; wsum[w][1] = v1; wsum[w][2] = v2; wsum[w][3] = v3;
      wsum[w][4] = v4; wsum[w][5] = v5; wsum[w][6] = v6; wsum[w][7] = v7;
    }
  }
  __syncthreads();
  if (threadIdx.x == 0) {
    PAcc r;
    r.pos_sum = wsum[0][0] + wsum[1][0] + wsum[2][0] + wsum[3][0];
    r.pos_w   = wsum[0][1] + wsum[1][1] + wsum[2][1] + wsum[3][1];
    r.tpx     = wsum[0][2] + wsum[1][2] + wsum[2][2] + wsum[3][2];
    r.sprx    = wsum[0][3] + wsum[1][3] + wsum[2][3] + wsum[3][3];
    r.mx      = fmaxf(fmaxf(wsum[0][4], wsum[1][4]), fmaxf(wsum[2][4], wsum[3][4]));
    r.sum_t   = wsum[0][5] + wsum[1][5] + wsum[2][5] + wsum[3][5];
    r.n_tis   = wsum[0][6] + wsum[1][6] + wsum[2][6] + wsum[3][6];
    r.bce0    = wsum[0][7] + wsum[1][7] + wsum[2][7] + wsum[3][7];
    pacc[(size_t)b * CHUNKS + chunk] = r;
    unsigned any3 = (r.n_tis != (float)PIXB) ? 1u : 0u;   // any pixel with m!=1
    s_any3 = any3;
    flags[(size_t)b * CHUNKS + chunk] = any3;
  }
  __syncthreads();

  // non-atomic coalesced flush (partial3 only if any m!=1 pixel existed)
  {
    unsigned* d1 = partial1 + ((size_t)b * CHUNKS + chunk) * NBINS;
    for (int i = threadIdx.x; i < NBINS; i += 256) d1[i] = hist1[i];
    if (s_any3) {
      unsigned* d3 = partial3 + ((size_t)b * CHUNKS + chunk) * (NBINS / 2);
      for (int i = threadIdx.x; i < NBINS / 2; i += 256) d3[i] = hist3p[i];
    }
  }
}

// ---------------- K2 (k_tail): slice reduce -> per-image scan -> final combine ----------------
__global__ __launch_bounds__(256) void k_tail(const unsigned* __restrict__ partial1,
                                              const unsigned* __restrict__ partial3,
                                              const unsigned* __restrict__ flags,
                                              u64* __restrict__ ghist,
                                              const PAcc* __restrict__ pacc,
                                              PAcc* __restrict__ accImg,
                                              AccR* __restrict__ acc,
                                              unsigned* __restrict__ tickets,
                                              float* __restrict__ out)
{
  const int img = blockIdx.y;          // 16
  const int slice = blockIdx.x;        // NBINS/256 = 16
  const int t = threadIdx.x;
  __shared__ unsigned sA[256], sB[256], sC[256];
  __shared__ float sf[256], sg[256];
  __shared__ unsigned s_flags[CHUNKS];
  __shared__ PAcc half[2];
  __shared__ unsigned s_do, ng_total_sh;

  if (t < CHUNKS) s_flags[t] = flags[(size_t)img * CHUNKS + t];
  __syncthreads();

  // ---- phase 1: reduce this slice's 256 bins across 96 partials ----
  {
    const int bin = slice * 256 + t;
    const unsigned* s1 = partial1 + (size_t)img * CHUNKS * NBINS + bin;
    const unsigned* s3 = partial3 + (size_t)img * CHUNKS * (NBINS / 2) + (bin >> 1);
    const unsigned sh3 = (bin & 1) << 4;
    unsigned c = 0, q = 0, n0 = 0;
    #pragma unroll 4
    for (int p = 0; p < CHUNKS; ++p) {
      unsigned v = s1[(size_t)p * NBINS];
      c += v & 0xFFFFu; q += v >> 16;
      if (s_flags[p]) n0 += (s3[(size_t)p * (NBINS / 2)] >> sh3) & 0xFFFFu;
    }
    unsigned negtis = (c - q) - n0;    // #(t==0 && m==1) in bin
    ghist[(size_t)img * NBINS + bin] = (u64)c | ((u64)q << 20) | ((u64)negtis << 40);
  }

  // ---- phase 1b: pacc reduce (slice 0; barriers are block-wide) ----
  {
    PAcc v;
    v.pos_sum = v.pos_w = v.tpx = v.sprx = v.mx = v.sum_t = v.n_tis = v.bce0 = 0.f;
    if (slice == 0 && t < CHUNKS) v = pacc[(size_t)img * CHUNKS + t];
    v.pos_sum = wred_sum(v.pos_sum); v.pos_w = wred_sum(v.pos_w);
    v.tpx = wred_sum(v.tpx); v.sprx = wred_sum(v.sprx);
    v.mx = wred_max(v.mx); v.sum_t = wred_sum(v.sum_t);
    v.n_tis = wred_sum(v.n_tis); v.bce0 = wred_sum(v.bce0);
    if (t < 128 && (t & 63) == 0) half[t >> 6] = v;
    __syncthreads();
    if (slice == 0 && t == 0) {
      PAcc r = half[0], h = half[1];
      r.pos_sum += h.pos_sum; r.pos_w += h.pos_w; r.tpx += h.tpx; r.sprx += h.sprx;
      r.mx = fmaxf(r.mx, h.mx); r.sum_t += h.sum_t; r.n_tis += h.n_tis; r.bce0 += h.bce0;
      accImg[img] = r;
    }
  }

  // ---- publish + ticket: last slice-block of this image runs the scan ----
  __threadfence();
  __syncthreads();
  if (t == 0) {
    unsigned ret = atomicAdd(&tickets[img], 1u);
    s_do = (ret == (unsigned)(NBINS / 256) - 1) ? 1u : 0u;
  }
  __syncthreads();
  if (!s_do) return;
  __threadfence();   // acquire: other slices' ghist/accImg writes

  // ---- phase 2: per-image descending walk (lovasz + OHEM) ----
  const u64* gh = ghist + (size_t)img * NBINS;
  const PAcc a = accImg[img];

  const unsigned sum_t = (unsigned)a.sum_t;
  const float p = (float)sum_t;
  const bool has_pos = sum_t > 0;
  const unsigned n_neg_total = (unsigned)PP - sum_t;
  const int CH = NBINS / 256;          // 16 bins per thread
  const float lov_d = LOV_RANGE / (float)NBINS;

  int n_pos = (int)a.pos_w;            // truncation like astype(int32)
  int n_remain = KALL - n_pos; if (n_remain < 0) n_remain = 0;

  u64 loc[16];
  unsigned tc = 0, tq = 0, tn = 0;
  #pragma unroll
  for (int k = 0; k < 16; ++k) {
    u64 v = gh[NBINS - 1 - (t * CH + k)];
    loc[k] = v;
    tc += (unsigned)(v & 0xFFFFFu);
    tq += (unsigned)((v >> 20) & 0xFFFFFu);
    tn += (unsigned)((v >> 40) & 0xFFFFFu);
  }
  sA[t] = tc; sB[t] = tq; sC[t] = tn;
  __syncthreads();
  if (t == 0) {
    unsigned aI = 0, aC = 0, aN = 0;
    for (int i = 0; i < 256; i++) {
      unsigned ci = sA[i], qi = sB[i], ni = sC[i];
      sA[i] = aI; sB[i] = aC; sC[i] = aN;
      aI += ci; aC += qi; aN += ni;
    }
    ng_total_sh = aN;
  }
  __syncthreads();

  float lov_local = 0.f, ns_local = 0.f;
  {
    unsigned I = sA[t], C = sB[t], NG = sC[t];
    float Jprev = has_pos ? (1.f - (p - (float)C) / (p + (float)I - (float)C)) : 0.f;
    #pragma unroll 4
    for (int k = 0; k < 16; ++k) {
      int j = NBINS - 1 - (t * CH + k);
      u64 v = loc[k];
      unsigned c = (unsigned)(v & 0xFFFFFu);
      if (c) {
        unsigned q = (unsigned)((v >> 20) & 0xFFFFFu);
        unsigned ng = (unsigned)((v >> 40) & 0xFFFFFu);
        float e = LOV_LO + ((float)j + 0.5f) * lov_d;
        if (has_pos) {
          float re = fmaxf(e, 0.f);
          if (n_neg_total > 0) {
            I += c; C += q;
            float Jb = 1.f - (p - (float)C) / (p + (float)I - (float)C);
            lov_local += re * (Jb - Jprev);
            Jprev = Jb;
          } else {
            double hi = (double)I + (double)c;
            double s = (hi * (hi + 1.0) - (double)I * ((double)I + 1.0)) * 0.5 / (double)p;
            lov_local += re * (float)s;
            I += c;
          }
        }
        if (n_remain > 0 && ng) {
          long long rem = (long long)n_remain - (long long)NG;
          unsigned take = rem <= 0 ? 0u : (rem >= (long long)ng ? ng : (unsigned)rem);
          if (take) {
            float l = e - 1.f;                         // negatives: e = 1 + l
            float nloss = fmaxf(l, 0.f) + __logf(1.f + __expf(-fabsf(l)));
            ns_local += (float)take * nloss;
          }
          NG += ng;
        }
      }
    }
  }
  sf[t] = lov_local; sg[t] = ns_local; __syncthreads();
  for (int off = 128; off > 0; off >>= 1) {
    if (t < off) { sf[t] += sf[t + off]; sg[t] += sg[t + off]; }
    __syncthreads();
  }

  if (t == 0) {
    float lov = sf[0];
    float neg_sum = sg[0];
    unsigned kept = (n_remain > 0)
        ? ((unsigned)n_remain < ng_total_sh ? (unsigned)n_remain : ng_total_sh) : 0u;
    float cnt = (float)n_pos + (float)kept;
    float ohem;
    if (cnt > 0.f) ohem = (a.pos_sum + neg_sum) / cnt;
    else ohem = (a.n_tis > 0.f) ? a.mx : a.bce0;
    float tp = a.tpx;
    float fn = p - tp;
    float fp = a.sprx - tp;
    float tv = (tp + 1e-6f) / (tp + 0.3f * fn + 0.7f * fp + 1e-6f);
    float ft = powf(fmaxf(1.f - tv, 0.f), 1.33f);
    acc[img].lov_i = lov; acc[img].ft_i = ft; acc[img].ohem_i = ohem;
    acc[img].posb = has_pos ? 1u : 0u;

    __threadfence();
    unsigned ret2 = atomicAdd(&tickets[16], 1u);
    if (ret2 == BB - 1) {               // last image: final combine
      __threadfence();
      volatile AccR* va = acc;
      float os = 0.f, fts = 0.f, lvs = 0.f; int np = 0;
      for (int i = 0; i < BB; i++) {
        os += va[i].ohem_i;
        if (va[i].posb) { np++; fts += va[i].ft_i; lvs += va[i].lov_i; }
      }
      float denom = (np > 0) ? (float)np : 1.f;
      float r = os / (float)BB;
      if (np > 0) r += fts / denom + 0.2f * (lvs / denom);
      out[0] = r;
    }
  }
}

extern "C" void kernel_launch(void* const* d_in, const int* in_sizes, int n_in,
                              void* d_out, int out_size, void* d_ws, size_t ws_size,
                              hipStream_t stream) {
  const float* logits  = (const float*)d_in[0];
  const int*   targets = (const int*)d_in[1];
  const float* mask    = (const float*)d_in[2];
  float* out = (float*)d_out;

  char* ws = (char*)d_ws;
  AccR*     acc      = (AccR*)ws;                        // 256 B
  unsigned* tickets  = (unsigned*)(ws + 256);            // 17 u32
  PAcc*     accImg   = (PAcc*)(ws + 512);                // 512 B
  PAcc*     pacc     = (PAcc*)(ws + 1024);               // 16*96*32 = 48 KB
  unsigned* flags    = (unsigned*)(ws + (64 << 10));     // 16*96*4 = 6 KB
  u64*      ghist    = (u64*)(ws + (128 << 10));         // 16*4096*8 = 512 KB
  unsigned* partial1 = (unsigned*)(ws + (1 << 20));      // 16*96*4096*4 = 25.2 MB
  unsigned* partial3 = (unsigned*)(ws + (1 << 20) + (size_t)BB * CHUNKS * NBINS * 4);  // 12.6 MB
  (void)in_sizes; (void)n_in; (void)out_size; (void)ws_size;

  dim3 g1(CHUNKS, BB, 1);        // 1536 blocks, 24KB LDS -> 6 blocks/CU
  k_main<<<g1, 256, 0, stream>>>(logits, targets, mask, pacc, partial1, partial3,
                                 flags, tickets);
  dim3 g2(NBINS / 256, BB, 1);   // 16 x 16 = 256 blocks
  k_tail<<<g2, 256, 0, stream>>>(partial1, partial3, flags, ghist, pacc, accImg,
                                 acc, tickets, out);
}

// Round 8
// 163.024 us; speedup vs baseline: 1.2148x; 1.2148x over previous
//
#include <hip/hip_runtime.h>
#include <math.h>

#define BB 16
#define PP (768*768)        // 589824
#define NBINS 2048
#define CHUNKS 128          // blocks per image; pixels/block = 4608 (fits u16)
#define PIXB (PP / CHUNKS)  // 4608
#define PC4  (PIXB / 4)     // 1152 float4 per chunk
#define KALL 176947         // int(P * 0.3)

#define LOV_LO (-17.0f)
#define LOV_RANGE 34.0f

typedef unsigned long long u64;

struct PAcc { float pos_sum, pos_w, tpx, sprx, mx, sum_t, n_tis, bce0; };   // 32 B
struct AccR { float lov_i, ft_i, ohem_i; unsigned posb; };                  // 16 B

__device__ inline float wred_sum(float v) {
  #pragma unroll
  for (int o = 32; o > 0; o >>= 1) v += __shfl_down(v, o, 64);
  return v;
}
__device__ inline float wred_max(float v) {
  #pragma unroll
  for (int o = 32; o > 0; o >>= 1) v = fmaxf(v, __shfl_down(v, o, 64));
  return v;
}

// ---------------- K1: fused pass; 12.3 KB LDS -> 8 blocks/CU (full occupancy) ----------------
// hist1[bin] = count | pos<<16 ; hist3p packed u16 = #(t==0 && m!=1) (fires only if m!=1)
__global__ __launch_bounds__(256) void k_main(const float* __restrict__ logits,
                                              const int* __restrict__ targets,
                                              const float* __restrict__ mask,
                                              PAcc* __restrict__ pacc,
                                              unsigned* __restrict__ partial1,
                                              unsigned* __restrict__ partial3,
                                              unsigned* __restrict__ flags)
{
  const int b = blockIdx.y;
  const int chunk = blockIdx.x;
  __shared__ unsigned hist1[NBINS];        // 8 KB
  __shared__ unsigned hist3p[NBINS / 2];   // 4 KB
  __shared__ float wsum[4][8];
  __shared__ unsigned s_any3;
  for (int i = threadIdx.x; i < NBINS; i += 256) hist1[i] = 0u;
  for (int i = threadIdx.x; i < NBINS / 2; i += 256) hist3p[i] = 0u;
  __syncthreads();

  const float4* l4 = (const float4*)(logits + (size_t)b * PP);
  const int4*   t4 = (const int4*)(targets + (size_t)b * PP);
  const float4* m4 = (const float4*)(mask + (size_t)b * PP);

  const float lov_scale = (float)NBINS / LOV_RANGE;

  float pos_sum = 0.f, pos_w = 0.f, tpa = 0.f, spra = 0.f, mx = 0.f;
  float sum_t = 0.f, n_tis = 0.f, bce0 = 0.f;

  // fallback loss_i[0] (chunk 0 / thread 0 only; block-sum propagates it)
  if (chunk == 0 && threadIdx.x == 0) {
    float l = logits[(size_t)b * PP];
    float tf = (float)targets[(size_t)b * PP];
    float m = mask[(size_t)b * PP];
    float ex = __expf(-fabsf(l));
    bce0 = (fmaxf(l, 0.f) + __logf(1.f + ex) - l * tf) * m;
  }

  const int base4 = chunk * PC4;

  for (int it = 0; it < 5; ++it) {
    int idx = it * 256 + threadIdx.x;
    if (idx < PC4) {
      int i = base4 + idx;
      float4 lv = l4[i]; int4 tv = t4[i]; float4 mv = m4[i];
      float ls[4] = {lv.x, lv.y, lv.z, lv.w};
      int   ts[4] = {tv.x, tv.y, tv.z, tv.w};
      float ms[4] = {mv.x, mv.y, mv.z, mv.w};
      #pragma unroll
      for (int c = 0; c < 4; ++c) {
        float l = ls[c]; int ti = ts[c]; float tf = (float)ti; float m = ms[c];
        float ex = __expf(-fabsf(l));                    // e^{-|l|}
        float lg = __logf(1.f + ex);                     // log1p(exp(-|l|)), 1+ex in (1,2]
        float loss = (fmaxf(l, 0.f) + lg - l * tf) * m;  // bce * mask
        float posw = tf * m;
        pos_sum = fmaf(loss, posw, pos_sum);
        pos_w  += posw;
        float pr = ((l >= 0.f) ? 1.f : ex) * __builtin_amdgcn_rcpf(1.f + ex);  // sigmoid
        spra += pr;
        tpa = fmaf(pr, tf, tpa);
        sum_t += tf;
        bool tis = (m == 1.0f);
        if (tis) { n_tis += 1.f; mx = fmaxf(mx, loss); }
        float s = fmaf(2.f, tf, -1.f);
        float e = fmaf(-l, s, 1.f);                      // lovasz error
        int bin = (int)((e - LOV_LO) * lov_scale);
        bin = bin < 0 ? 0 : (bin > NBINS - 1 ? NBINS - 1 : bin);
        atomicAdd(&hist1[bin], 1u | ((unsigned)ti << 16));
        if ((ti == 0) & !tis)                            // never fires when mask==1
          atomicAdd(&hist3p[bin >> 1], 1u << ((bin & 1) << 4));
      }
    }
  }

  // block-level scalar reduction -> pacc (non-atomic)
  {
    float v0 = wred_sum(pos_sum), v1 = wred_sum(pos_w), v2 = wred_sum(tpa);
    float v3 = wred_sum(spra), v4 = wred_max(mx), v5 = wred_sum(sum_t);
    float v6 = wred_sum(n_tis), v7 = wred_sum(bce0);
    int w = threadIdx.x >> 6, lane = threadIdx.x & 63;
    if (lane == 0) {
      wsum[w][0] = v0; wsum[w][1] = v1; wsum[w][2] = v2; wsum[w][3] = v3;
      wsum[w][4] = v4; wsum[w][5] = v5; wsum[w][6] = v6; wsum[w][7] = v7;
    }
  }
  __syncthreads();
  if (threadIdx.x == 0) {
    PAcc r;
    r.pos_sum = wsum[0][0] + wsum[1][0] + wsum[2][0] + wsum[3][0];
    r.pos_w   = wsum[0][1] + wsum[1][1] + wsum[2][1] + wsum[3][1];
    r.tpx     = wsum[0][2] + wsum[1][2] + wsum[2][2] + wsum[3][2];
    r.sprx    = wsum[0][3] + wsum[1][3] + wsum[2][3] + wsum[3][3];
    r.mx      = fmaxf(fmaxf(wsum[0][4], wsum[1][4]), fmaxf(wsum[2][4], wsum[3][4]));
    r.sum_t   = wsum[0][5] + wsum[1][5] + wsum[2][5] + wsum[3][5];
    r.n_tis   = wsum[0][6] + wsum[1][6] + wsum[2][6] + wsum[3][6];
    r.bce0    = wsum[0][7] + wsum[1][7] + wsum[2][7] + wsum[3][7];
    pacc[(size_t)b * CHUNKS + chunk] = r;
    unsigned any3 = (r.n_tis != (float)PIXB) ? 1u : 0u;   // any pixel with m!=1
    s_any3 = any3;
    flags[(size_t)b * CHUNKS + chunk] = any3;
  }
  __syncthreads();

  // non-atomic coalesced flush (partial3 only if any m!=1 pixel existed)
  {
    unsigned* d1 = partial1 + ((size_t)b * CHUNKS + chunk) * NBINS;
    for (int i = threadIdx.x; i < NBINS; i += 256) d1[i] = hist1[i];
    if (s_any3) {
      unsigned* d3 = partial3 + ((size_t)b * CHUNKS + chunk) * (NBINS / 2);
      for (int i = threadIdx.x; i < NBINS / 2; i += 256) d3[i] = hist3p[i];
    }
  }
}

// ---------------- K1b: branch-free partial reduce -> ghist; zero ticket ----------------
__global__ __launch_bounds__(256) void k_reduce(const unsigned* __restrict__ partial1,
                                                const unsigned* __restrict__ partial3,
                                                const unsigned* __restrict__ flags,
                                                u64* __restrict__ ghist,
                                                unsigned* __restrict__ tickets)
{
  const int img = blockIdx.y;          // 16
  const int slice = blockIdx.x;        // 32 slices x 64 bins
  const int t = threadIdx.x;
  const int lane = t & 63, g = t >> 6;           // 4 groups x 32 partials
  const int bin = slice * 64 + lane;
  __shared__ unsigned sC[256], sQ[256];
  __shared__ unsigned short s_list[CHUNKS];
  __shared__ int s_n;

  // hot loop: 32 strided loads, no branches
  const unsigned* s1 = partial1 + ((size_t)img * CHUNKS + (size_t)g * 32) * NBINS + bin;
  unsigned c = 0, q = 0;
  #pragma unroll 8
  for (int p = 0; p < 32; ++p) {
    unsigned v = s1[(size_t)p * NBINS];
    c += v & 0xFFFFu; q += v >> 16;
  }
  sC[t] = c; sQ[t] = q;

  if (t == 0) {   // compact flagged-chunk list (empty when mask==1 everywhere)
    int n = 0;
    for (int p = 0; p < CHUNKS; ++p) if (flags[(size_t)img * CHUNKS + p]) s_list[n++] = (unsigned short)p;
    s_n = n;
  }
  __syncthreads();

  if (t < 64) {
    unsigned ct = sC[t] + sC[64 + t] + sC[128 + t] + sC[192 + t];
    unsigned qt = sQ[t] + sQ[64 + t] + sQ[128 + t] + sQ[192 + t];
    const int bn = slice * 64 + t;
    unsigned n0 = 0;
    const unsigned sh = (bn & 1) << 4;
    for (int k = 0; k < s_n; ++k) {
      int p = s_list[k];
      n0 += (partial3[((size_t)img * CHUNKS + p) * (NBINS / 2) + (bn >> 1)] >> sh) & 0xFFFFu;
    }
    unsigned negtis = (ct - qt) - n0;            // #(t==0 && m==1) in bin
    ghist[(size_t)img * NBINS + bn] = (u64)ct | ((u64)qt << 20) | ((u64)negtis << 40);
  }
  if (slice == 0 && img == 0 && t == 0) tickets[0] = 0u;
}

// ---------------- K2: pacc reduce + per-image descending walk + last-block combine ----------------
__global__ __launch_bounds__(256) void k_scan(const PAcc* __restrict__ pacc,
                                              const u64* __restrict__ ghist,
                                              AccR* __restrict__ acc,
                                              unsigned* __restrict__ tickets,
                                              float* __restrict__ out)
{
  const int b = blockIdx.x;
  const int t = threadIdx.x;
  __shared__ unsigned sA[256], sB[256], sC[256];
  __shared__ float sf[256], sg[256];
  __shared__ PAcc halfw[4];
  __shared__ PAcc aS;
  __shared__ unsigned ng_total_sh;

  // ---- phase 0: reduce pacc[b][0..CHUNKS) (CHUNKS=128 -> waves 0,1 carry data) ----
  {
    PAcc v;
    v.pos_sum = v.pos_w = v.tpx = v.sprx = v.mx = v.sum_t = v.n_tis = v.bce0 = 0.f;
    if (t < CHUNKS) v = pacc[(size_t)b * CHUNKS + t];
    v.pos_sum = wred_sum(v.pos_sum); v.pos_w = wred_sum(v.pos_w);
    v.tpx = wred_sum(v.tpx); v.sprx = wred_sum(v.sprx);
    v.mx = wred_max(v.mx); v.sum_t = wred_sum(v.sum_t);
    v.n_tis = wred_sum(v.n_tis); v.bce0 = wred_sum(v.bce0);
    if ((t & 63) == 0) halfw[t >> 6] = v;
    __syncthreads();
    if (t == 0) {
      PAcc r = halfw[0];
      for (int w = 1; w < 4; ++w) {
        PAcc h = halfw[w];
        r.pos_sum += h.pos_sum; r.pos_w += h.pos_w; r.tpx += h.tpx; r.sprx += h.sprx;
        r.mx = fmaxf(r.mx, h.mx); r.sum_t += h.sum_t; r.n_tis += h.n_tis; r.bce0 += h.bce0;
      }
      aS = r;
    }
    __syncthreads();
  }
  const PAcc a = aS;

  const unsigned sum_t = (unsigned)a.sum_t;
  const float p = (float)sum_t;
  const bool has_pos = sum_t > 0;
  const unsigned n_neg_total = (unsigned)PP - sum_t;
  const int CH = NBINS / 256;          // 8 bins per thread
  const float lov_d = LOV_RANGE / (float)NBINS;

  int n_pos = (int)a.pos_w;            // truncation like astype(int32)
  int n_remain = KALL - n_pos; if (n_remain < 0) n_remain = 0;

  const u64* gh = ghist + (size_t)b * NBINS;
  u64 loc[8];
  unsigned tc = 0, tq = 0, tn = 0;
  #pragma unroll
  for (int k = 0; k < 8; ++k) {
    u64 v = gh[NBINS - 1 - (t * CH + k)];
    loc[k] = v;
    tc += (unsigned)(v & 0xFFFFFu);
    tq += (unsigned)((v >> 20) & 0xFFFFFu);
    tn += (unsigned)((v >> 40) & 0xFFFFFu);
  }
  sA[t] = tc; sB[t] = tq; sC[t] = tn;
  __syncthreads();
  if (t == 0) {
    unsigned aI = 0, aC = 0, aN = 0;
    for (int i = 0; i < 256; i++) {
      unsigned ci = sA[i], qi = sB[i], ni = sC[i];
      sA[i] = aI; sB[i] = aC; sC[i] = aN;
      aI += ci; aC += qi; aN += ni;
    }
    ng_total_sh = aN;
  }
  __syncthreads();

  float lov_local = 0.f, ns_local = 0.f;
  {
    unsigned I = sA[t], C = sB[t], NG = sC[t];
    float Jprev = has_pos ? (1.f - (p - (float)C) / (p + (float)I - (float)C)) : 0.f;
    #pragma unroll 4
    for (int k = 0; k < 8; ++k) {
      int j = NBINS - 1 - (t * CH + k);
      u64 v = loc[k];
      unsigned c = (unsigned)(v & 0xFFFFFu);
      if (c) {
        unsigned q = (unsigned)((v >> 20) & 0xFFFFFu);
        unsigned ng = (unsigned)((v >> 40) & 0xFFFFFu);
        float e = LOV_LO + ((float)j + 0.5f) * lov_d;
        if (has_pos) {
          float re = fmaxf(e, 0.f);
          if (n_neg_total > 0) {
            I += c; C += q;
            float Jb = 1.f - (p - (float)C) / (p + (float)I - (float)C);
            lov_local += re * (Jb - Jprev);
            Jprev = Jb;
          } else {
            double hi = (double)I + (double)c;
            double s = (hi * (hi + 1.0) - (double)I * ((double)I + 1.0)) * 0.5 / (double)p;
            lov_local += re * (float)s;
            I += c;
          }
        }
        if (n_remain > 0 && ng) {
          long long rem = (long long)n_remain - (long long)NG;
          unsigned take = rem <= 0 ? 0u : (rem >= (long long)ng ? ng : (unsigned)rem);
          if (take) {
            float l = e - 1.f;                         // negatives: e = 1 + l
            float nloss = fmaxf(l, 0.f) + __logf(1.f + __expf(-fabsf(l)));
            ns_local += (float)take * nloss;
          }
          NG += ng;
        }
      }
    }
  }
  sf[t] = lov_local; sg[t] = ns_local; __syncthreads();
  for (int off = 128; off > 0; off >>= 1) {
    if (t < off) { sf[t] += sf[t + off]; sg[t] += sg[t + off]; }
    __syncthreads();
  }

  if (t == 0) {
    float lov = sf[0];
    float neg_sum = sg[0];
    unsigned kept = (n_remain > 0)
        ? ((unsigned)n_remain < ng_total_sh ? (unsigned)n_remain : ng_total_sh) : 0u;
    float cnt = (float)n_pos + (float)kept;
    float ohem;
    if (cnt > 0.f) ohem = (a.pos_sum + neg_sum) / cnt;
    else ohem = (a.n_tis > 0.f) ? a.mx : a.bce0;
    float tp = a.tpx;
    float fn = p - tp;
    float fp = a.sprx - tp;
    float tv = (tp + 1e-6f) / (tp + 0.3f * fn + 0.7f * fp + 1e-6f);
    float ft = powf(fmaxf(1.f - tv, 0.f), 1.33f);
    acc[b].lov_i = lov; acc[b].ft_i = ft; acc[b].ohem_i = ohem;
    acc[b].posb = has_pos ? 1u : 0u;

    __threadfence();
    unsigned ret = atomicAdd(&tickets[0], 1u);
    if (ret == BB - 1) {                 // last image: final combine
      __threadfence();
      volatile AccR* va = acc;
      float os = 0.f, fts = 0.f, lvs = 0.f; int np = 0;
      for (int i = 0; i < BB; i++) {
        os += va[i].ohem_i;
        if (va[i].posb) { np++; fts += va[i].ft_i; lvs += va[i].lov_i; }
      }
      float denom = (np > 0) ? (float)np : 1.f;
      float r = os / (float)BB;
      if (np > 0) r += fts / denom + 0.2f * (lvs / denom);
      out[0] = r;
    }
  }
}

extern "C" void kernel_launch(void* const* d_in, const int* in_sizes, int n_in,
                              void* d_out, int out_size, void* d_ws, size_t ws_size,
                              hipStream_t stream) {
  const float* logits  = (const float*)d_in[0];
  const int*   targets = (const int*)d_in[1];
  const float* mask    = (const float*)d_in[2];
  float* out = (float*)d_out;

  char* ws = (char*)d_ws;
  AccR*     acc      = (AccR*)ws;                        // 256 B
  unsigned* tickets  = (unsigned*)(ws + 256);            // u32
  PAcc*     pacc     = (PAcc*)(ws + 1024);               // 16*128*32 = 64 KB
  unsigned* flags    = (unsigned*)(ws + (80 << 10));     // 16*128*4 = 8 KB
  u64*      ghist    = (u64*)(ws + (96 << 10));          // 16*2048*8 = 256 KB
  unsigned* partial1 = (unsigned*)(ws + (512 << 10));    // 16*128*2048*4 = 16.8 MB
  unsigned* partial3 = (unsigned*)(ws + (512 << 10) + (size_t)BB * CHUNKS * NBINS * 4);  // 8.4 MB
  (void)in_sizes; (void)n_in; (void)out_size; (void)ws_size;

  dim3 g1(CHUNKS, BB, 1);        // 2048 blocks, 12.3 KB LDS -> 8 blocks/CU (full occupancy)
  k_main<<<g1, 256, 0, stream>>>(logits, targets, mask, pacc, partial1, partial3, flags);
  dim3 g2(NBINS / 64, BB, 1);    // 32 x 16 = 512 blocks
  k_reduce<<<g2, 256, 0, stream>>>(partial1, partial3, flags, ghist, tickets);
  k_scan<<<BB, 256, 0, stream>>>(pacc, ghist, acc, tickets, out);
}

// Round 9
// 161.470 us; speedup vs baseline: 1.2265x; 1.0096x over previous
//
#include <hip/hip_runtime.h>
#include <math.h>

#define BB 16
#define PP (768*768)        // 589824
#define NBINS 2048
#define CHUNKS 128          // blocks per image; pixels/block = 4608 (fits u16)
#define PIXB (PP / CHUNKS)  // 4608
#define PC4  (PIXB / 4)     // 1152 float4 per chunk = 4.5 * 256
#define KALL 176947         // int(P * 0.3)

#define LOV_LO (-17.0f)
#define LOV_RANGE 34.0f

typedef unsigned long long u64;

struct PAcc { float pos_sum, pos_w, tpx, sprx, mx, sum_t, n_tis, bce0; };   // 32 B
struct AccR { float lov_i, ft_i, ohem_i; unsigned posb; };                  // 16 B

__device__ inline float wred_sum(float v) {
  #pragma unroll
  for (int o = 32; o > 0; o >>= 1) v += __shfl_down(v, o, 64);
  return v;
}
__device__ inline float wred_max(float v) {
  #pragma unroll
  for (int o = 32; o > 0; o >>= 1) v = fmaxf(v, __shfl_down(v, o, 64));
  return v;
}

// ---------------- K1: fused pass; all loads hoisted up front for MLP ----------------
// hist1[bin] = count | pos<<16 ; hist3p packed u16 = #(t==0 && m!=1) (fires only if m!=1)
__global__ __launch_bounds__(256, 6) void k_main(const float* __restrict__ logits,
                                                 const int* __restrict__ targets,
                                                 const float* __restrict__ mask,
                                                 PAcc* __restrict__ pacc,
                                                 unsigned* __restrict__ partial1,
                                                 unsigned* __restrict__ partial3,
                                                 unsigned* __restrict__ flags)
{
  const int b = blockIdx.y;
  const int chunk = blockIdx.x;
  __shared__ unsigned hist1[NBINS];        // 8 KB
  __shared__ unsigned hist3p[NBINS / 2];   // 4 KB
  __shared__ float wsum[4][8];
  __shared__ unsigned s_any3;
  for (int i = threadIdx.x; i < NBINS; i += 256) hist1[i] = 0u;
  for (int i = threadIdx.x; i < NBINS / 2; i += 256) hist3p[i] = 0u;
  __syncthreads();

  const float4* l4 = (const float4*)(logits + (size_t)b * PP);
  const int4*   t4 = (const int4*)(targets + (size_t)b * PP);
  const float4* m4 = (const float4*)(mask + (size_t)b * PP);

  const float lov_scale = (float)NBINS / LOV_RANGE;

  float pos_sum = 0.f, pos_w = 0.f, tpa = 0.f, spra = 0.f, mx = 0.f;
  float sum_t = 0.f, n_tis = 0.f, bce0 = 0.f;

  // fallback loss_i[0] (chunk 0 / thread 0 only; block-sum propagates it)
  if (chunk == 0 && threadIdx.x == 0) {
    float l = logits[(size_t)b * PP];
    float tf = (float)targets[(size_t)b * PP];
    float m = mask[(size_t)b * PP];
    float ex = __expf(-fabsf(l));
    bce0 = (fmaxf(l, 0.f) + __logf(1.f + ex) - l * tf) * m;
  }

  const int base4 = chunk * PC4;
  const bool tail = threadIdx.x < 128;     // wave-uniform (waves 0,1)

  // ---- hoist ALL loads: 4 full iterations + half-iteration, 15 float4-equivalents in flight ----
  float4 L[4]; int4 T[4]; float4 M[4];
  #pragma unroll
  for (int it = 0; it < 4; ++it) {
    int i = base4 + it * 256 + threadIdx.x;
    L[it] = l4[i]; T[it] = t4[i]; M[it] = m4[i];
  }
  float4 Lt; int4 Tt; float4 Mt;
  if (tail) {
    int i = base4 + 1024 + threadIdx.x;
    Lt = l4[i]; Tt = t4[i]; Mt = m4[i];
  }

  auto px = [&](float l, int ti, float m) {
    float tf = (float)ti;
    float ex = __expf(-fabsf(l));                    // e^{-|l|}
    float lg = __logf(1.f + ex);                     // log1p(exp(-|l|)), 1+ex in (1,2]
    float loss = (fmaxf(l, 0.f) + lg - l * tf) * m;  // bce * mask
    float posw = tf * m;
    pos_sum = fmaf(loss, posw, pos_sum);
    pos_w  += posw;
    float pr = ((l >= 0.f) ? 1.f : ex) * __builtin_amdgcn_rcpf(1.f + ex);  // sigmoid
    spra += pr;
    tpa = fmaf(pr, tf, tpa);
    sum_t += tf;
    bool tis = (m == 1.0f);
    if (tis) { n_tis += 1.f; mx = fmaxf(mx, loss); }
    float s = fmaf(2.f, tf, -1.f);
    float e = fmaf(-l, s, 1.f);                      // lovasz error
    int bin = (int)((e - LOV_LO) * lov_scale);
    bin = bin < 0 ? 0 : (bin > NBINS - 1 ? NBINS - 1 : bin);
    atomicAdd(&hist1[bin], 1u | ((unsigned)ti << 16));
    if ((ti == 0) & !tis)                            // never fires when mask==1
      atomicAdd(&hist3p[bin >> 1], 1u << ((bin & 1) << 4));
  };

  #pragma unroll
  for (int it = 0; it < 4; ++it) {
    px(L[it].x, T[it].x, M[it].x); px(L[it].y, T[it].y, M[it].y);
    px(L[it].z, T[it].z, M[it].z); px(L[it].w, T[it].w, M[it].w);
  }
  if (tail) {
    px(Lt.x, Tt.x, Mt.x); px(Lt.y, Tt.y, Mt.y);
    px(Lt.z, Tt.z, Mt.z); px(Lt.w, Tt.w, Mt.w);
  }

  // block-level scalar reduction -> pacc (non-atomic)
  {
    float v0 = wred_sum(pos_sum), v1 = wred_sum(pos_w), v2 = wred_sum(tpa);
    float v3 = wred_sum(spra), v4 = wred_max(mx), v5 = wred_sum(sum_t);
    float v6 = wred_sum(n_tis), v7 = wred_sum(bce0);
    int w = threadIdx.x >> 6, lane = threadIdx.x & 63;
    if (lane == 0) {
      wsum[w][0] = v0; wsum[w][1] = v1; wsum[w][2] = v2; wsum[w][3] = v3;
      wsum[w][4] = v4; wsum[w][5] = v5; wsum[w][6] = v6; wsum[w][7] = v7;
    }
  }
  __syncthreads();
  if (threadIdx.x == 0) {
    PAcc r;
    r.pos_sum = wsum[0][0] + wsum[1][0] + wsum[2][0] + wsum[3][0];
    r.pos_w   = wsum[0][1] + wsum[1][1] + wsum[2][1] + wsum[3][1];
    r.tpx     = wsum[0][2] + wsum[1][2] + wsum[2][2] + wsum[3][2];
    r.sprx    = wsum[0][3] + wsum[1][3] + wsum[2][3] + wsum[3][3];
    r.mx      = fmaxf(fmaxf(wsum[0][4], wsum[1][4]), fmaxf(wsum[2][4], wsum[3][4]));
    r.sum_t   = wsum[0][5] + wsum[1][5] + wsum[2][5] + wsum[3][5];
    r.n_tis   = wsum[0][6] + wsum[1][6] + wsum[2][6] + wsum[3][6];
    r.bce0    = wsum[0][7] + wsum[1][7] + wsum[2][7] + wsum[3][7];
    pacc[(size_t)b * CHUNKS + chunk] = r;
    unsigned any3 = (r.n_tis != (float)PIXB) ? 1u : 0u;   // any pixel with m!=1
    s_any3 = any3;
    flags[(size_t)b * CHUNKS + chunk] = any3;
  }
  __syncthreads();

  // non-atomic coalesced flush (partial3 only if any m!=1 pixel existed)
  {
    unsigned* d1 = partial1 + ((size_t)b * CHUNKS + chunk) * NBINS;
    for (int i = threadIdx.x; i < NBINS; i += 256) d1[i] = hist1[i];
    if (s_any3) {
      unsigned* d3 = partial3 + ((size_t)b * CHUNKS + chunk) * (NBINS / 2);
      for (int i = threadIdx.x; i < NBINS / 2; i += 256) d3[i] = hist3p[i];
    }
  }
}

// ---------------- K1b: branch-free partial reduce -> ghist; zero ticket ----------------
__global__ __launch_bounds__(256) void k_reduce(const unsigned* __restrict__ partial1,
                                                const unsigned* __restrict__ partial3,
                                                const unsigned* __restrict__ flags,
                                                u64* __restrict__ ghist,
                                                unsigned* __restrict__ tickets)
{
  const int img = blockIdx.y;          // 16
  const int slice = blockIdx.x;        // 32 slices x 64 bins
  const int t = threadIdx.x;
  const int lane = t & 63, g = t >> 6;           // 4 groups x 32 partials
  const int bin = slice * 64 + lane;
  __shared__ unsigned sC[256], sQ[256];
  __shared__ unsigned short s_list[CHUNKS];
  __shared__ int s_n;

  // hot loop: 32 strided loads, no branches
  const unsigned* s1 = partial1 + ((size_t)img * CHUNKS + (size_t)g * 32) * NBINS + bin;
  unsigned c = 0, q = 0;
  #pragma unroll 8
  for (int p = 0; p < 32; ++p) {
    unsigned v = s1[(size_t)p * NBINS];
    c += v & 0xFFFFu; q += v >> 16;
  }
  sC[t] = c; sQ[t] = q;

  if (t == 0) {   // compact flagged-chunk list (empty when mask==1 everywhere)
    int n = 0;
    for (int p = 0; p < CHUNKS; ++p) if (flags[(size_t)img * CHUNKS + p]) s_list[n++] = (unsigned short)p;
    s_n = n;
  }
  __syncthreads();

  if (t < 64) {
    unsigned ct = sC[t] + sC[64 + t] + sC[128 + t] + sC[192 + t];
    unsigned qt = sQ[t] + sQ[64 + t] + sQ[128 + t] + sQ[192 + t];
    const int bn = slice * 64 + t;
    unsigned n0 = 0;
    const unsigned sh = (bn & 1) << 4;
    for (int k = 0; k < s_n; ++k) {
      int p = s_list[k];
      n0 += (partial3[((size_t)img * CHUNKS + p) * (NBINS / 2) + (bn >> 1)] >> sh) & 0xFFFFu;
    }
    unsigned negtis = (ct - qt) - n0;            // #(t==0 && m==1) in bin
    ghist[(size_t)img * NBINS + bn] = (u64)ct | ((u64)qt << 20) | ((u64)negtis << 40);
  }
  if (slice == 0 && img == 0 && t == 0) tickets[0] = 0u;
}

// ---------------- K2: pacc reduce + per-image descending walk + last-block combine ----------------
__global__ __launch_bounds__(256) void k_scan(const PAcc* __restrict__ pacc,
                                              const u64* __restrict__ ghist,
                                              AccR* __restrict__ acc,
                                              unsigned* __restrict__ tickets,
                                              float* __restrict__ out)
{
  const int b = blockIdx.x;
  const int t = threadIdx.x;
  __shared__ unsigned sA[256], sB[256], sC[256];
  __shared__ float sf[256], sg[256];
  __shared__ PAcc halfw[4];
  __shared__ PAcc aS;
  __shared__ unsigned ng_total_sh;

  // ---- phase 0: reduce pacc[b][0..CHUNKS) ----
  {
    PAcc v;
    v.pos_sum = v.pos_w = v.tpx = v.sprx = v.mx = v.sum_t = v.n_tis = v.bce0 = 0.f;
    if (t < CHUNKS) v = pacc[(size_t)b * CHUNKS + t];
    v.pos_sum = wred_sum(v.pos_sum); v.pos_w = wred_sum(v.pos_w);
    v.tpx = wred_sum(v.tpx); v.sprx = wred_sum(v.sprx);
    v.mx = wred_max(v.mx); v.sum_t = wred_sum(v.sum_t);
    v.n_tis = wred_sum(v.n_tis); v.bce0 = wred_sum(v.bce0);
    if ((t & 63) == 0) halfw[t >> 6] = v;
    __syncthreads();
    if (t == 0) {
      PAcc r = halfw[0];
      for (int w = 1; w < 4; ++w) {
        PAcc h = halfw[w];
        r.pos_sum += h.pos_sum; r.pos_w += h.pos_w; r.tpx += h.tpx; r.sprx += h.sprx;
        r.mx = fmaxf(r.mx, h.mx); r.sum_t += h.sum_t; r.n_tis += h.n_tis; r.bce0 += h.bce0;
      }
      aS = r;
    }
    __syncthreads();
  }
  const PAcc a = aS;

  const unsigned sum_t = (unsigned)a.sum_t;
  const float p = (float)sum_t;
  const bool has_pos = sum_t > 0;
  const unsigned n_neg_total = (unsigned)PP - sum_t;
  const int CH = NBINS / 256;          // 8 bins per thread
  const float lov_d = LOV_RANGE / (float)NBINS;

  int n_pos = (int)a.pos_w;            // truncation like astype(int32)
  int n_remain = KALL - n_pos; if (n_remain < 0) n_remain = 0;

  const u64* gh = ghist + (size_t)b * NBINS;
  u64 loc[8];
  unsigned tc = 0, tq = 0, tn = 0;
  #pragma unroll
  for (int k = 0; k < 8; ++k) {
    u64 v = gh[NBINS - 1 - (t * CH + k)];
    loc[k] = v;
    tc += (unsigned)(v & 0xFFFFFu);
    tq += (unsigned)((v >> 20) & 0xFFFFFu);
    tn += (unsigned)((v >> 40) & 0xFFFFFu);
  }
  sA[t] = tc; sB[t] = tq; sC[t] = tn;
  __syncthreads();
  if (t == 0) {
    unsigned aI = 0, aC = 0, aN = 0;
    for (int i = 0; i < 256; i++) {
      unsigned ci = sA[i], qi = sB[i], ni = sC[i];
      sA[i] = aI; sB[i] = aC; sC[i] = aN;
      aI += ci; aC += qi; aN += ni;
    }
    ng_total_sh = aN;
  }
  __syncthreads();

  float lov_local = 0.f, ns_local = 0.f;
  {
    unsigned I = sA[t], C = sB[t], NG = sC[t];
    float Jprev = has_pos ? (1.f - (p - (float)C) / (p + (float)I - (float)C)) : 0.f;
    #pragma unroll 4
    for (int k = 0; k < 8; ++k) {
      int j = NBINS - 1 - (t * CH + k);
      u64 v = loc[k];
      unsigned c = (unsigned)(v & 0xFFFFFu);
      if (c) {
        unsigned q = (unsigned)((v >> 20) & 0xFFFFFu);
        unsigned ng = (unsigned)((v >> 40) & 0xFFFFFu);
        float e = LOV_LO + ((float)j + 0.5f) * lov_d;
        if (has_pos) {
          float re = fmaxf(e, 0.f);
          if (n_neg_total > 0) {
            I += c; C += q;
            float Jb = 1.f - (p - (float)C) / (p + (float)I - (float)C);
            lov_local += re * (Jb - Jprev);
            Jprev = Jb;
          } else {
            double hi = (double)I + (double)c;
            double s = (hi * (hi + 1.0) - (double)I * ((double)I + 1.0)) * 0.5 / (double)p;
            lov_local += re * (float)s;
            I += c;
          }
        }
        if (n_remain > 0 && ng) {
          long long rem = (long long)n_remain - (long long)NG;
          unsigned take = rem <= 0 ? 0u : (rem >= (long long)ng ? ng : (unsigned)rem);
          if (take) {
            float l = e - 1.f;                         // negatives: e = 1 + l
            float nloss = fmaxf(l, 0.f) + __logf(1.f + __expf(-fabsf(l)));
            ns_local += (float)take * nloss;
          }
          NG += ng;
        }
      }
    }
  }
  sf[t] = lov_local; sg[t] = ns_local; __syncthreads();
  for (int off = 128; off > 0; off >>= 1) {
    if (t < off) { sf[t] += sf[t + off]; sg[t] += sg[t + off]; }
    __syncthreads();
  }

  if (t == 0) {
    float lov = sf[0];
    float neg_sum = sg[0];
    unsigned kept = (n_remain > 0)
        ? ((unsigned)n_remain < ng_total_sh ? (unsigned)n_remain : ng_total_sh) : 0u;
    float cnt = (float)n_pos + (float)kept;
    float ohem;
    if (cnt > 0.f) ohem = (a.pos_sum + neg_sum) / cnt;
    else ohem = (a.n_tis > 0.f) ? a.mx : a.bce0;
    float tp = a.tpx;
    float fn = p - tp;
    float fp = a.sprx - tp;
    float tv = (tp + 1e-6f) / (tp + 0.3f * fn + 0.7f * fp + 1e-6f);
    float ft = powf(fmaxf(1.f - tv, 0.f), 1.33f);
    acc[b].lov_i = lov; acc[b].ft_i = ft; acc[b].ohem_i = ohem;
    acc[b].posb = has_pos ? 1u : 0u;

    __threadfence();
    unsigned ret = atomicAdd(&tickets[0], 1u);
    if (ret == BB - 1) {                 // last image: final combine
      __threadfence();
      volatile AccR* va = acc;
      float os = 0.f, fts = 0.f, lvs = 0.f; int np = 0;
      for (int i = 0; i < BB; i++) {
        os += va[i].ohem_i;
        if (va[i].posb) { np++; fts += va[i].ft_i; lvs += va[i].lov_i; }
      }
      float denom = (np > 0) ? (float)np : 1.f;
      float r = os / (float)BB;
      if (np > 0) r += fts / denom + 0.2f * (lvs / denom);
      out[0] = r;
    }
  }
}

extern "C" void kernel_launch(void* const* d_in, const int* in_sizes, int n_in,
                              void* d_out, int out_size, void* d_ws, size_t ws_size,
                              hipStream_t stream) {
  const float* logits  = (const float*)d_in[0];
  const int*   targets = (const int*)d_in[1];
  const float* mask    = (const float*)d_in[2];
  float* out = (float*)d_out;

  char* ws = (char*)d_ws;
  AccR*     acc      = (AccR*)ws;                        // 256 B
  unsigned* tickets  = (unsigned*)(ws + 256);            // u32
  PAcc*     pacc     = (PAcc*)(ws + 1024);               // 16*128*32 = 64 KB
  unsigned* flags    = (unsigned*)(ws + (80 << 10));     // 16*128*4 = 8 KB
  u64*      ghist    = (u64*)(ws + (96 << 10));          // 16*2048*8 = 256 KB
  unsigned* partial1 = (unsigned*)(ws + (512 << 10));    // 16*128*2048*4 = 16.8 MB
  unsigned* partial3 = (unsigned*)(ws + (512 << 10) + (size_t)BB * CHUNKS * NBINS * 4);  // 8.4 MB
  (void)in_sizes; (void)n_in; (void)out_size; (void)ws_size;

  dim3 g1(CHUNKS, BB, 1);        // 2048 blocks, 12.3 KB LDS, VGPR<=85 -> 6 blocks/CU
  k_main<<<g1, 256, 0, stream>>>(logits, targets, mask, pacc, partial1, partial3, flags);
  dim3 g2(NBINS / 64, BB, 1);    // 32 x 16 = 512 blocks
  k_reduce<<<g2, 256, 0, stream>>>(partial1, partial3, flags, ghist, tickets);
  k_scan<<<BB, 256, 0, stream>>>(pacc, ghist, acc, tickets, out);
}